// Round 1
// 639.302 us; speedup vs baseline: 1.0612x; 1.0612x over previous
//
#include <hip/hip_runtime.h>

// ---------------------------------------------------------------------------
// Fully-fused WaveNet forward (MFMA). R6 = 590us dispatch, 2 blocks/CU, but
// WRITE_SIZE 847MB vs 134MB ideal + FETCH 580MB => ~1.3KB/thread scratch
// spill traffic: (512,4) caps unified regs at 128 while live set (sk 64 +
// acc 40 + temps) ~140. R7: split conv/res jn-range into groups of 3+2 so
// conv accumulators shrink 40->24 regs (no spill), replace the two IEEE
// divisions in the gate with one v_rcp, and do all bf16 packing with
// v_cvt_pk_bf16_f32 (1 instr / 2 elems instead of 4 instr / elem).
// ---------------------------------------------------------------------------

typedef __attribute__((ext_vector_type(8))) short short8;   // 8 bf16 (A/B frag)
typedef __attribute__((ext_vector_type(4))) float f32x4;    // accumulator
typedef __attribute__((ext_vector_type(2))) unsigned int uint2v; // 8B pack

#define T_TOK 8192
#define TT    128     // central cols per block
#define HALO  32
#define XSTE  136     // x LDS col stride (128 ch + 8 pad), 272B = 17*16B (odd chunk)
#define GSTE  72      // g LDS col stride (64 ch + 8 pad), 144B = 9*16B (odd chunk)
#define SSTE  264     // s/t1 LDS col stride (256 ch + 8 pad), 528B = 33*16B (odd chunk)
#define X_OFF 0
#define G_OFF 43520                  // 160*136*2
#define S_OFF 0                      // sb OVERLAYS xb/gb (epilogue only)
#define LDS_BYTES 67584              // max(43520+23040, 128*264*2=67584)

// fragment-section bases in d_ws (bf16 elems)
#define FI  0          // init conv: 2 taps * 8 mt * 8 kc * 512
#define FD  65536      // dil conv: 12 * 2 * 8 * 4 * 512
#define FS  458752     // skip:     12 * 16 * 2 * 512   (scaled by 1/12)
#define FR  655360     // res:      12 * 8 * 2 * 512
#define FO1 753664     // out1:     16 * 8 * 512
#define FO2 819200     // out2:     16 * 8 * 512
#define FRAG_TOTAL 884736
#define BSK_BYTE_OFF  (FRAG_TOTAL * 2)          // 256 floats
#define EMBF_BYTE_OFF (BSK_BYTE_OFF + 1024)     // 65536 bf16
#define PREP_TOTAL (FRAG_TOTAL + 256 + 65536)   // = 950528 = 3713*256

#define MFMA(a, b, c) __builtin_amdgcn_mfma_f32_16x16x32_bf16(a, b, c, 0, 0, 0)

__device__ __forceinline__ unsigned short f2b(float f) {
  unsigned int x = __builtin_bit_cast(unsigned int, f);
  return (unsigned short)((x + 0x7fffu + ((x >> 16) & 1u)) >> 16);  // RNE
}

// two f32 -> packed bf16x2 (RNE), single VOP3
__device__ __forceinline__ unsigned int cvt_pk_bf16(float lo, float hi) {
  unsigned int r;
  asm("v_cvt_pk_bf16_f32 %0, %1, %2" : "=v"(r) : "v"(lo), "v"(hi));
  return r;
}

// ---------------- prep: swizzle weights into A-fragment order ----------------
// frag element (outer, lane, j): value = W[mt*16 + (lane&15)][kc*32 + (lane>>4)*8 + j]
__global__ void __launch_bounds__(256) prep_kernel(
    const float* __restrict__ emb,
    const float* __restrict__ w_init,
    const float* __restrict__ w_dil,
    const float* __restrict__ w_skip,
    const float* __restrict__ w_res,
    const float* __restrict__ w_out1,
    const float* __restrict__ w_out2,
    const float* __restrict__ b_skip,
    unsigned short* __restrict__ frags,
    float* __restrict__ bsk,
    unsigned short* __restrict__ embf)
{
  int flat = blockIdx.x * 256 + threadIdx.x;
  if (flat < FRAG_TOTAL) {
    float val;
    if (flat < FD) {                       // init conv  W[128][256][2]
      int rel = flat;
      int j = rel & 7, lane = (rel >> 3) & 63, outer = rel >> 9;
      int kc = outer & 7, mt = (outer >> 3) & 7, tap = outer >> 6;
      int m = mt * 16 + (lane & 15);
      int k = kc * 32 + (lane >> 4) * 8 + j;
      val = w_init[(m * 256 + k) * 2 + tap];
    } else if (flat < FS) {                // dil conv  W[12][128][128][2]
      int rel = flat - FD;
      int j = rel & 7, lane = (rel >> 3) & 63, outer = rel >> 9;
      int kc = outer & 3, mt = (outer >> 2) & 7, tap = (outer >> 5) & 1, l = outer >> 6;
      int m = mt * 16 + (lane & 15);
      int k = kc * 32 + (lane >> 4) * 8 + j;
      val = w_dil[((l * 128 + m) * 128 + k) * 2 + tap];
    } else if (flat < FR) {                // skip  W[12][256][64], scaled 1/12
      int rel = flat - FS;
      int j = rel & 7, lane = (rel >> 3) & 63, outer = rel >> 9;
      int kc = outer & 1, mt = (outer >> 1) & 15, l = outer >> 5;
      int m = mt * 16 + (lane & 15);
      int k = kc * 32 + (lane >> 4) * 8 + j;
      val = w_skip[(l * 256 + m) * 64 + k] * (1.0f / 12.0f);
    } else if (flat < FO1) {               // res  W[12][128][64]
      int rel = flat - FR;
      int j = rel & 7, lane = (rel >> 3) & 63, outer = rel >> 9;
      int kc = outer & 1, mt = (outer >> 1) & 7, l = outer >> 4;
      int m = mt * 16 + (lane & 15);
      int k = kc * 32 + (lane >> 4) * 8 + j;
      val = w_res[(l * 128 + m) * 64 + k];
    } else if (flat < FO2) {               // out1  W[256][256]
      int rel = flat - FO1;
      int j = rel & 7, lane = (rel >> 3) & 63, outer = rel >> 9;
      int kc = outer & 7, mt = outer >> 3;
      int m = mt * 16 + (lane & 15);
      int k = kc * 32 + (lane >> 4) * 8 + j;
      val = w_out1[m * 256 + k];
    } else {                               // out2  W[256][256]
      int rel = flat - FO2;
      int j = rel & 7, lane = (rel >> 3) & 63, outer = rel >> 9;
      int kc = outer & 7, mt = outer >> 3;
      int m = mt * 16 + (lane & 15);
      int k = kc * 32 + (lane >> 4) * 8 + j;
      val = w_out2[m * 256 + k];
    }
    frags[flat] = f2b(val);
  } else if (flat < FRAG_TOTAL + 256) {    // combined skip bias: sum_l b_skip / 12
    int ch = flat - FRAG_TOTAL;
    float s = 0.f;
    for (int l = 0; l < 12; l++) s += b_skip[l * 256 + ch];
    bsk[ch] = s * (1.0f / 12.0f);
  } else if (flat < PREP_TOTAL) {          // bf16 copy of emb [256][256]
    int i = flat - FRAG_TOTAL - 256;
    embf[i] = f2b(emb[i]);
  }
}

// ------------------- per-group helpers (registers: acc[2][GN]) -------------

template<int G0, int GN>
__device__ __forceinline__ void phaseA_grp(
    const int* __restrict__ tokens, const unsigned short* __restrict__ embf,
    const unsigned short* __restrict__ frags, const float* __restrict__ b_init,
    unsigned short* __restrict__ xb,
    int bb, int tb, int colbase, int wm, int lane, int q)
{
  const short8 zero8 = {0, 0, 0, 0, 0, 0, 0, 0};
  int tk[GN][2];
#pragma unroll
  for (int jn = 0; jn < GN; jn++) {
    int col = colbase + (G0 + jn) * 16;
#pragma unroll
    for (int s = 0; s < 2; s++) {
      int shift = s ? 0 : 1;     // tap0 <-> x[t-1], tap1 <-> x[t]
      int tsrc = tb + col - shift;
      tk[jn][s] = (tsrc >= 0) ? tokens[bb * T_TOK + tsrc] : -1;
    }
  }
  f32x4 acc[2][GN];
#pragma unroll
  for (int i = 0; i < 2; i++) {
    f32x4 bv = *(const f32x4*)(b_init + (wm + 4 * i) * 16 + q * 4);
#pragma unroll
    for (int jn = 0; jn < GN; jn++) acc[i][jn] = bv;
  }
#pragma unroll
  for (int s = 0; s < 2; s++) {
#pragma unroll
    for (int kc = 0; kc < 8; kc++) {
      short8 a0 = *(const short8*)(frags + FI + (((s * 8 + wm    ) * 8 + kc) * 64 + lane) * 8);
      short8 a1 = *(const short8*)(frags + FI + (((s * 8 + wm + 4) * 8 + kc) * 64 + lane) * 8);
#pragma unroll
      for (int jn = 0; jn < GN; jn++) {
        int t = tk[jn][s];
        int ts = t < 0 ? 0 : t;
        short8 bv = *(const short8*)(embf + ts * 256 + kc * 32 + q * 8);
        if (t < 0) bv = zero8;
        acc[0][jn] = MFMA(a0, bv, acc[0][jn]);
        acc[1][jn] = MFMA(a1, bv, acc[1][jn]);
      }
    }
  }
#pragma unroll
  for (int i = 0; i < 2; i++) {
#pragma unroll
    for (int jn = 0; jn < GN; jn++) {
      int col = colbase + (G0 + jn) * 16;
      unsigned int u0 = cvt_pk_bf16(acc[i][jn][0], acc[i][jn][1]);
      unsigned int u1 = cvt_pk_bf16(acc[i][jn][2], acc[i][jn][3]);
      if (tb + col < 0) { u0 = 0; u1 = 0; }
      *(uint2v*)(xb + col * XSTE + (wm + 4 * i) * 16 + q * 4) = (uint2v){u0, u1};
    }
  }
}

template<int G0, int GN>
__device__ __forceinline__ void dil_gate_grp(
    const unsigned short* __restrict__ frags, const float* __restrict__ b_dil,
    const unsigned short* __restrict__ xb, unsigned short* __restrict__ gb,
    int layer, int tb, int colbase, int wm, int lane, int q)
{
  f32x4 acc[2][GN];
#pragma unroll
  for (int i = 0; i < 2; i++) {
    f32x4 bv = *(const f32x4*)(b_dil + layer * 128 + (wm + 4 * i) * 16 + q * 4);
#pragma unroll
    for (int jn = 0; jn < GN; jn++) acc[i][jn] = bv;
  }
#pragma unroll
  for (int s = 0; s < 2; s++) {
    const int shift = s ? 0 : 2;
#pragma unroll
    for (int kc = 0; kc < 4; kc++) {
      short8 a0 = *(const short8*)(frags + FD + ((((layer * 2 + s) * 8 + wm    ) * 4 + kc) * 64 + lane) * 8);
      short8 a1 = *(const short8*)(frags + FD + ((((layer * 2 + s) * 8 + wm + 4) * 4 + kc) * 64 + lane) * 8);
#pragma unroll
      for (int jn = 0; jn < GN; jn++) {
        int c = colbase + (G0 + jn) * 16 - shift; if (c < 0) c = 0;  // clamp
        short8 bv = *(const short8*)(xb + c * XSTE + kc * 32 + q * 8);
        acc[0][jn] = MFMA(a0, bv, acc[0][jn]);
        acc[1][jn] = MFMA(a1, bv, acc[1][jn]);
      }
    }
  }
  // gate: tanh(xt)*sigmoid(xs) = (A-1) / ((A+1)*(1+B)), A=e^{2xt}, B=e^{-xs}
  // one v_rcp instead of two IEEE divisions; clamp xt so A stays finite.
#pragma unroll
  for (int jn = 0; jn < GN; jn++) {
    int col = colbase + (G0 + jn) * 16;
    float g[4];
#pragma unroll
    for (int r = 0; r < 4; r++) {
      float xt = fminf(acc[0][jn][r], 40.f);
      float A = __expf(2.f * xt);
      float Bs = __expf(-acc[1][jn][r]);
      g[r] = (A - 1.f) * __builtin_amdgcn_rcpf((A + 1.f) * (1.f + Bs));
    }
    unsigned int u0 = cvt_pk_bf16(g[0], g[1]);
    unsigned int u1 = cvt_pk_bf16(g[2], g[3]);
    if (tb + col < 0) { u0 = 0; u1 = 0; }
    *(uint2v*)(gb + col * GSTE + wm * 16 + q * 4) = (uint2v){u0, u1};
  }
}

template<int G0, int GN>
__device__ __forceinline__ void res_upd_grp(
    const unsigned short* __restrict__ frags, const float* __restrict__ b_res,
    unsigned short* __restrict__ xb, const unsigned short* __restrict__ gb,
    int layer, int tb, int colbase, int wm, int lane, int q)
{
  f32x4 acc[2][GN];
#pragma unroll
  for (int i = 0; i < 2; i++) {
    f32x4 bv = *(const f32x4*)(b_res + layer * 128 + (wm + 4 * i) * 16 + q * 4);
#pragma unroll
    for (int jn = 0; jn < GN; jn++) acc[i][jn] = bv;
  }
#pragma unroll
  for (int kc = 0; kc < 2; kc++) {
    short8 a0 = *(const short8*)(frags + FR + (((layer * 8 + wm    ) * 2 + kc) * 64 + lane) * 8);
    short8 a1 = *(const short8*)(frags + FR + (((layer * 8 + wm + 4) * 2 + kc) * 64 + lane) * 8);
#pragma unroll
    for (int jn = 0; jn < GN; jn++) {
      int col = colbase + (G0 + jn) * 16;
      short8 bv = *(const short8*)(gb + col * GSTE + kc * 32 + q * 8);
      acc[0][jn] = MFMA(a0, bv, acc[0][jn]);
      acc[1][jn] = MFMA(a1, bv, acc[1][jn]);
    }
  }
#pragma unroll
  for (int i = 0; i < 2; i++) {
#pragma unroll
    for (int jn = 0; jn < GN; jn++) {
      int col = colbase + (G0 + jn) * 16;
      unsigned short* p = xb + col * XSTE + (wm + 4 * i) * 16 + q * 4;
      uint2v old = *(const uint2v*)p;
      float x0 = __builtin_bit_cast(float, old[0] << 16);
      float x1 = __builtin_bit_cast(float, old[0] & 0xffff0000u);
      float x2 = __builtin_bit_cast(float, old[1] << 16);
      float x3 = __builtin_bit_cast(float, old[1] & 0xffff0000u);
      unsigned int u0 = cvt_pk_bf16(acc[i][jn][0] + x0, acc[i][jn][1] + x1);
      unsigned int u1 = cvt_pk_bf16(acc[i][jn][2] + x2, acc[i][jn][3] + x3);
      if (tb + col < 0) { u0 = 0; u1 = 0; }
      *(uint2v*)p = (uint2v){u0, u1};
    }
  }
}

// ------------------------------- main kernel -------------------------------
extern "C" __global__ void __launch_bounds__(512, 4) wavenet_main(
    const int* __restrict__ tokens,
    const unsigned short* __restrict__ embf,
    const unsigned short* __restrict__ frags,
    const float* __restrict__ bsk,
    const float* __restrict__ b_init,
    const float* __restrict__ b_dil,
    const float* __restrict__ b_res,
    const float* __restrict__ b_out1,
    const float* __restrict__ b_out2,
    float* __restrict__ out)
{
  extern __shared__ char lds[];
  unsigned short* xb = (unsigned short*)(lds + X_OFF);  // [160][136] x (bf16)
  unsigned short* gb = (unsigned short*)(lds + G_OFF);  // [160][72]  g (bf16)
  unsigned short* sb = (unsigned short*)(lds + S_OFF);  // [128][264] s/t1 (overlay)

  const int tid = threadIdx.x;
  const int lane = tid & 63;
  const int w = tid >> 6;        // 0..7
  const int l16 = lane & 15;
  const int q = lane >> 4;
  const int wm = w & 3;          // conv M-group: M-tiles {wm, wm+4} (gate pairing)
  const int wn = w >> 2;         // conv N-group (0..1)
  const int bb = blockIdx.x >> 6;
  const int chunk = blockIdx.x & 63;
  const int tb = chunk * TT - HALO;   // abs t of buffer col 0
  const int colbase = wn * 80 + l16;  // ncol(jn) = colbase + jn*16

  f32x4 sk[2][8];    // persistent skip accumulators (then out1/out2)

  // ---- phase A: init conv (B-frags gathered straight from bf16 emb copy) ----
  phaseA_grp<0, 3>(tokens, embf, frags, b_init, xb, bb, tb, colbase, wm, lane, q);
  phaseA_grp<3, 2>(tokens, embf, frags, b_init, xb, bb, tb, colbase, wm, lane, q);

  // init persistent skip accumulators with combined bias
#pragma unroll
  for (int i = 0; i < 2; i++) {
    f32x4 bv = *(const f32x4*)(bsk + (2 * w + i) * 16 + q * 4);
#pragma unroll
    for (int jt = 0; jt < 8; jt++) sk[i][jt] = bv;
  }
  __syncthreads();

  // ---- 12 layers ----
  for (int layer = 0; layer < 12; layer++) {
    dil_gate_grp<0, 3>(frags, b_dil, xb, gb, layer, tb, colbase, wm, lane, q);
    dil_gate_grp<3, 2>(frags, b_dil, xb, gb, layer, tb, colbase, wm, lane, q);
    __syncthreads();
    // skip GEMM into persistent accumulators (central 128 cols only)
#pragma unroll
    for (int kc = 0; kc < 2; kc++) {
      short8 a0 = *(const short8*)(frags + FS + (((layer * 16 + 2 * w    ) * 2 + kc) * 64 + lane) * 8);
      short8 a1 = *(const short8*)(frags + FS + (((layer * 16 + 2 * w + 1) * 2 + kc) * 64 + lane) * 8);
#pragma unroll
      for (int jt = 0; jt < 8; jt++) {
        short8 bv = *(const short8*)(gb + (HALO + jt * 16 + l16) * GSTE + kc * 32 + q * 8);
        sk[0][jt] = MFMA(a0, bv, sk[0][jt]);
        sk[1][jt] = MFMA(a1, bv, sk[1][jt]);
      }
    }
    // res GEMM (all 160 cols) then x += res
    res_upd_grp<0, 3>(frags, b_res, xb, gb, layer, tb, colbase, wm, lane, q);
    res_upd_grp<3, 2>(frags, b_res, xb, gb, layer, tb, colbase, wm, lane, q);
    __syncthreads();
  }

  // ---- epilogue: s = relu(skip_mean) -> out1 -> relu -> out2 ----
  // sb overlays xb/gb; all xb/gb reads completed before the final layer barrier.
#pragma unroll
  for (int i = 0; i < 2; i++) {
#pragma unroll
    for (int jt = 0; jt < 8; jt++) {
      unsigned int u0 = cvt_pk_bf16(fmaxf(sk[i][jt][0], 0.f), fmaxf(sk[i][jt][1], 0.f));
      unsigned int u1 = cvt_pk_bf16(fmaxf(sk[i][jt][2], 0.f), fmaxf(sk[i][jt][3], 0.f));
      *(uint2v*)(sb + (jt * 16 + l16) * SSTE + (2 * w + i) * 16 + q * 4) = (uint2v){u0, u1};
    }
  }
  __syncthreads();
  // out1
#pragma unroll
  for (int i = 0; i < 2; i++) {
    f32x4 bv = *(const f32x4*)(b_out1 + (2 * w + i) * 16 + q * 4);
#pragma unroll
    for (int jt = 0; jt < 8; jt++) sk[i][jt] = bv;
  }
#pragma unroll
  for (int kc = 0; kc < 8; kc++) {
    short8 a0 = *(const short8*)(frags + FO1 + (((2 * w    ) * 8 + kc) * 64 + lane) * 8);
    short8 a1 = *(const short8*)(frags + FO1 + (((2 * w + 1) * 8 + kc) * 64 + lane) * 8);
#pragma unroll
    for (int jt = 0; jt < 8; jt++) {
      short8 bv = *(const short8*)(sb + (jt * 16 + l16) * SSTE + kc * 32 + q * 8);
      sk[0][jt] = MFMA(a0, bv, sk[0][jt]);
      sk[1][jt] = MFMA(a1, bv, sk[1][jt]);
    }
  }
  unsigned int t1p[2][8][2];
#pragma unroll
  for (int i = 0; i < 2; i++) {
#pragma unroll
    for (int jt = 0; jt < 8; jt++) {
      t1p[i][jt][0] = cvt_pk_bf16(fmaxf(sk[i][jt][0], 0.f), fmaxf(sk[i][jt][1], 0.f));
      t1p[i][jt][1] = cvt_pk_bf16(fmaxf(sk[i][jt][2], 0.f), fmaxf(sk[i][jt][3], 0.f));
    }
  }
  __syncthreads();   // all reads of s done before overwrite
#pragma unroll
  for (int i = 0; i < 2; i++) {
#pragma unroll
    for (int jt = 0; jt < 8; jt++)
      *(uint2v*)(sb + (jt * 16 + l16) * SSTE + (2 * w + i) * 16 + q * 4) =
          (uint2v){t1p[i][jt][0], t1p[i][jt][1]};
  }
  __syncthreads();
  // out2
#pragma unroll
  for (int i = 0; i < 2; i++) {
    f32x4 bv = *(const f32x4*)(b_out2 + (2 * w + i) * 16 + q * 4);
#pragma unroll
    for (int jt = 0; jt < 8; jt++) sk[i][jt] = bv;
  }
#pragma unroll
  for (int kc = 0; kc < 8; kc++) {
    short8 a0 = *(const short8*)(frags + FO2 + (((2 * w    ) * 8 + kc) * 64 + lane) * 8);
    short8 a1 = *(const short8*)(frags + FO2 + (((2 * w + 1) * 8 + kc) * 64 + lane) * 8);
#pragma unroll
    for (int jt = 0; jt < 8; jt++) {
      short8 bv = *(const short8*)(sb + (jt * 16 + l16) * SSTE + kc * 32 + q * 8);
      sk[0][jt] = MFMA(a0, bv, sk[0][jt]);
      sk[1][jt] = MFMA(a1, bv, sk[1][jt]);
    }
  }
  // write out [B, V=256, T] as FLOAT32
  const int t0 = chunk * TT;
#pragma unroll
  for (int i = 0; i < 2; i++) {
#pragma unroll
    for (int jt = 0; jt < 8; jt++) {
#pragma unroll
      for (int r = 0; r < 4; r++) {
        int v = (2 * w + i) * 16 + q * 4 + r;
        int t = t0 + jt * 16 + l16;
        out[((size_t)(bb * 256 + v) << 13) + t] = sk[i][jt][r];
      }
    }
  }
}

// ------------------------------- launcher ----------------------------------
extern "C" void kernel_launch(void* const* d_in, const int* in_sizes, int n_in,
                              void* d_out, int out_size, void* d_ws, size_t ws_size,
                              hipStream_t stream) {
  (void)in_sizes; (void)n_in; (void)out_size; (void)ws_size;
  const int*   tokens = (const int*)d_in[0];
  const float* emb    = (const float*)d_in[1];
  const float* w_init = (const float*)d_in[2];
  const float* b_init = (const float*)d_in[3];
  const float* w_dil  = (const float*)d_in[4];
  const float* b_dil  = (const float*)d_in[5];
  const float* w_res  = (const float*)d_in[6];
  const float* b_res  = (const float*)d_in[7];
  const float* w_skip = (const float*)d_in[8];
  const float* b_skip = (const float*)d_in[9];
  const float* w_out1 = (const float*)d_in[10];
  const float* b_out1 = (const float*)d_in[11];
  const float* w_out2 = (const float*)d_in[12];
  const float* b_out2 = (const float*)d_in[13];

  unsigned short* frags = (unsigned short*)d_ws;
  float* bsk = (float*)((char*)d_ws + BSK_BYTE_OFF);
  unsigned short* embf = (unsigned short*)((char*)d_ws + EMBF_BYTE_OFF);

  prep_kernel<<<dim3(PREP_TOTAL / 256), dim3(256), 0, stream>>>(
      emb, w_init, w_dil, w_skip, w_res, w_out1, w_out2, b_skip,
      frags, bsk, embf);

  // opt-in to >64KB dynamic LDS (no-op/harmless where already allowed)
  (void)hipFuncSetAttribute((const void*)wavenet_main,
                            hipFuncAttributeMaxDynamicSharedMemorySize, LDS_BYTES);

  wavenet_main<<<dim3(1024), dim3(512), LDS_BYTES, stream>>>(
      tokens, embf, frags, bsk, b_init, b_dil, b_res, b_out1, b_out2,
      (float*)d_out);
}

// Round 6
// 553.255 us; speedup vs baseline: 1.2262x; 1.1555x over previous
//
#include <hip/hip_runtime.h>

// ---------------------------------------------------------------------------
// Fully-fused WaveNet forward (MFMA). R7 (548us PASS, (512,4)) spills ~800MB
// scratch: sk[2][8] (=256ch x 128t / 512thr = 64 f32 regs) + acc + temps
// exceeds the 128-reg budget. R8-R11 showed this kernel miscompiles under
// ANY budget/grouping perturbation (deterministic absmax, source-invariant)
// -> keep the exact R7 helper code and (512,4), and shrink the live set
// geometrically instead: R12 = TT 128->64. sk[2][4]=32 regs, acc[2][3]=24,
// total live ~100 < 128 -> no spills. Helpers instantiated ONCE each at
// GN=3 (the exact instantiation R7 compiled correctly). Buffer 96 cols
// (32 halo + 64 central), 2048 blocks, LDS 39936B.
// ---------------------------------------------------------------------------

typedef __attribute__((ext_vector_type(8))) short short8;   // 8 bf16 (A/B frag)
typedef __attribute__((ext_vector_type(4))) float f32x4;    // accumulator
typedef __attribute__((ext_vector_type(2))) unsigned int uint2v; // 8B pack

#define T_TOK 8192
#define TT    64      // central cols per block
#define HALO  32
#define NCOLS 96      // buffer cols = HALO + TT
#define XSTE  136     // x LDS col stride (128 ch + 8 pad)
#define GSTE  72      // g LDS col stride (64 ch + 8 pad)
#define SSTE  264     // s/t1 LDS col stride (256 ch + 8 pad)
#define X_OFF 0
#define G_OFF 26112                  // 96*136*2
#define S_OFF 0                      // sb OVERLAYS xb/gb (epilogue only)
#define LDS_BYTES 39936              // max(26112+13824, 64*264*2=33792)

// fragment-section bases in d_ws (bf16 elems)
#define FI  0          // init conv: 2 taps * 8 mt * 8 kc * 512
#define FD  65536      // dil conv: 12 * 2 * 8 * 4 * 512
#define FS  458752     // skip:     12 * 16 * 2 * 512   (scaled by 1/12)
#define FR  655360     // res:      12 * 8 * 2 * 512
#define FO1 753664     // out1:     16 * 8 * 512
#define FO2 819200     // out2:     16 * 8 * 512
#define FRAG_TOTAL 884736
#define BSK_BYTE_OFF  (FRAG_TOTAL * 2)          // 256 floats
#define EMBF_BYTE_OFF (BSK_BYTE_OFF + 1024)     // 65536 bf16
#define PREP_TOTAL (FRAG_TOTAL + 256 + 65536)   // = 950528 = 3713*256

#define MFMA(a, b, c) __builtin_amdgcn_mfma_f32_16x16x32_bf16(a, b, c, 0, 0, 0)

__device__ __forceinline__ unsigned short f2b(float f) {
  unsigned int x = __builtin_bit_cast(unsigned int, f);
  return (unsigned short)((x + 0x7fffu + ((x >> 16) & 1u)) >> 16);  // RNE
}

// two f32 -> packed bf16x2 (RNE), single VOP3
__device__ __forceinline__ unsigned int cvt_pk_bf16(float lo, float hi) {
  unsigned int r;
  asm("v_cvt_pk_bf16_f32 %0, %1, %2" : "=v"(r) : "v"(lo), "v"(hi));
  return r;
}

// ---------------- prep: swizzle weights into A-fragment order ----------------
// frag element (outer, lane, j): value = W[mt*16 + (lane&15)][kc*32 + (lane>>4)*8 + j]
__global__ void __launch_bounds__(256) prep_kernel(
    const float* __restrict__ emb,
    const float* __restrict__ w_init,
    const float* __restrict__ w_dil,
    const float* __restrict__ w_skip,
    const float* __restrict__ w_res,
    const float* __restrict__ w_out1,
    const float* __restrict__ w_out2,
    const float* __restrict__ b_skip,
    unsigned short* __restrict__ frags,
    float* __restrict__ bsk,
    unsigned short* __restrict__ embf)
{
  int flat = blockIdx.x * 256 + threadIdx.x;
  if (flat < FRAG_TOTAL) {
    float val;
    if (flat < FD) {                       // init conv  W[128][256][2]
      int rel = flat;
      int j = rel & 7, lane = (rel >> 3) & 63, outer = rel >> 9;
      int kc = outer & 7, mt = (outer >> 3) & 7, tap = outer >> 6;
      int m = mt * 16 + (lane & 15);
      int k = kc * 32 + (lane >> 4) * 8 + j;
      val = w_init[(m * 256 + k) * 2 + tap];
    } else if (flat < FS) {                // dil conv  W[12][128][128][2]
      int rel = flat - FD;
      int j = rel & 7, lane = (rel >> 3) & 63, outer = rel >> 9;
      int kc = outer & 3, mt = (outer >> 2) & 7, tap = (outer >> 5) & 1, l = outer >> 6;
      int m = mt * 16 + (lane & 15);
      int k = kc * 32 + (lane >> 4) * 8 + j;
      val = w_dil[((l * 128 + m) * 128 + k) * 2 + tap];
    } else if (flat < FR) {                // skip  W[12][256][64], scaled 1/12
      int rel = flat - FS;
      int j = rel & 7, lane = (rel >> 3) & 63, outer = rel >> 9;
      int kc = outer & 1, mt = (outer >> 1) & 15, l = outer >> 5;
      int m = mt * 16 + (lane & 15);
      int k = kc * 32 + (lane >> 4) * 8 + j;
      val = w_skip[(l * 256 + m) * 64 + k] * (1.0f / 12.0f);
    } else if (flat < FO1) {               // res  W[12][128][64]
      int rel = flat - FR;
      int j = rel & 7, lane = (rel >> 3) & 63, outer = rel >> 9;
      int kc = outer & 1, mt = (outer >> 1) & 7, l = outer >> 4;
      int m = mt * 16 + (lane & 15);
      int k = kc * 32 + (lane >> 4) * 8 + j;
      val = w_res[(l * 128 + m) * 64 + k];
    } else if (flat < FO2) {               // out1  W[256][256]
      int rel = flat - FO1;
      int j = rel & 7, lane = (rel >> 3) & 63, outer = rel >> 9;
      int kc = outer & 7, mt = outer >> 3;
      int m = mt * 16 + (lane & 15);
      int k = kc * 32 + (lane >> 4) * 8 + j;
      val = w_out1[m * 256 + k];
    } else {                               // out2  W[256][256]
      int rel = flat - FO2;
      int j = rel & 7, lane = (rel >> 3) & 63, outer = rel >> 9;
      int kc = outer & 7, mt = outer >> 3;
      int m = mt * 16 + (lane & 15);
      int k = kc * 32 + (lane >> 4) * 8 + j;
      val = w_out2[m * 256 + k];
    }
    frags[flat] = f2b(val);
  } else if (flat < FRAG_TOTAL + 256) {    // combined skip bias: sum_l b_skip / 12
    int ch = flat - FRAG_TOTAL;
    float s = 0.f;
    for (int l = 0; l < 12; l++) s += b_skip[l * 256 + ch];
    bsk[ch] = s * (1.0f / 12.0f);
  } else if (flat < PREP_TOTAL) {          // bf16 copy of emb [256][256]
    int i = flat - FRAG_TOTAL - 256;
    embf[i] = f2b(emb[i]);
  }
}

// ------------------- per-group helpers (registers: acc[2][GN]) -------------

template<int G0, int GN>
__device__ __forceinline__ void phaseA_grp(
    const int* __restrict__ tokens, const unsigned short* __restrict__ embf,
    const unsigned short* __restrict__ frags, const float* __restrict__ b_init,
    unsigned short* __restrict__ xb,
    int bb, int tb, int colbase, int wm, int lane, int q)
{
  const short8 zero8 = {0, 0, 0, 0, 0, 0, 0, 0};
  int tk[GN][2];
#pragma unroll
  for (int jn = 0; jn < GN; jn++) {
    int col = colbase + (G0 + jn) * 16;
#pragma unroll
    for (int s = 0; s < 2; s++) {
      int shift = s ? 0 : 1;     // tap0 <-> x[t-1], tap1 <-> x[t]
      int tsrc = tb + col - shift;
      tk[jn][s] = (tsrc >= 0) ? tokens[bb * T_TOK + tsrc] : -1;
    }
  }
  f32x4 acc[2][GN];
#pragma unroll
  for (int i = 0; i < 2; i++) {
    f32x4 bv = *(const f32x4*)(b_init + (wm + 4 * i) * 16 + q * 4);
#pragma unroll
    for (int jn = 0; jn < GN; jn++) acc[i][jn] = bv;
  }
#pragma unroll
  for (int s = 0; s < 2; s++) {
#pragma unroll
    for (int kc = 0; kc < 8; kc++) {
      short8 a0 = *(const short8*)(frags + FI + (((s * 8 + wm    ) * 8 + kc) * 64 + lane) * 8);
      short8 a1 = *(const short8*)(frags + FI + (((s * 8 + wm + 4) * 8 + kc) * 64 + lane) * 8);
#pragma unroll
      for (int jn = 0; jn < GN; jn++) {
        int t = tk[jn][s];
        int ts = t < 0 ? 0 : t;
        short8 bv = *(const short8*)(embf + ts * 256 + kc * 32 + q * 8);
        if (t < 0) bv = zero8;
        acc[0][jn] = MFMA(a0, bv, acc[0][jn]);
        acc[1][jn] = MFMA(a1, bv, acc[1][jn]);
      }
    }
  }
#pragma unroll
  for (int i = 0; i < 2; i++) {
#pragma unroll
    for (int jn = 0; jn < GN; jn++) {
      int col = colbase + (G0 + jn) * 16;
      unsigned int u0 = cvt_pk_bf16(acc[i][jn][0], acc[i][jn][1]);
      unsigned int u1 = cvt_pk_bf16(acc[i][jn][2], acc[i][jn][3]);
      if (tb + col < 0) { u0 = 0; u1 = 0; }
      *(uint2v*)(xb + col * XSTE + (wm + 4 * i) * 16 + q * 4) = (uint2v){u0, u1};
    }
  }
}

template<int G0, int GN>
__device__ __forceinline__ void dil_gate_grp(
    const unsigned short* __restrict__ frags, const float* __restrict__ b_dil,
    const unsigned short* __restrict__ xb, unsigned short* __restrict__ gb,
    int layer, int tb, int colbase, int wm, int lane, int q)
{
  f32x4 acc[2][GN];
#pragma unroll
  for (int i = 0; i < 2; i++) {
    f32x4 bv = *(const f32x4*)(b_dil + layer * 128 + (wm + 4 * i) * 16 + q * 4);
#pragma unroll
    for (int jn = 0; jn < GN; jn++) acc[i][jn] = bv;
  }
#pragma unroll
  for (int s = 0; s < 2; s++) {
    const int shift = s ? 0 : 2;
#pragma unroll
    for (int kc = 0; kc < 4; kc++) {
      short8 a0 = *(const short8*)(frags + FD + ((((layer * 2 + s) * 8 + wm    ) * 4 + kc) * 64 + lane) * 8);
      short8 a1 = *(const short8*)(frags + FD + ((((layer * 2 + s) * 8 + wm + 4) * 4 + kc) * 64 + lane) * 8);
#pragma unroll
      for (int jn = 0; jn < GN; jn++) {
        int c = colbase + (G0 + jn) * 16 - shift; if (c < 0) c = 0;  // clamp
        short8 bv = *(const short8*)(xb + c * XSTE + kc * 32 + q * 8);
        acc[0][jn] = MFMA(a0, bv, acc[0][jn]);
        acc[1][jn] = MFMA(a1, bv, acc[1][jn]);
      }
    }
  }
  // gate: tanh(xt)*sigmoid(xs) = (A-1) / ((A+1)*(1+B)), A=e^{2xt}, B=e^{-xs}
  // one v_rcp instead of two IEEE divisions; clamp xt so A stays finite.
#pragma unroll
  for (int jn = 0; jn < GN; jn++) {
    int col = colbase + (G0 + jn) * 16;
    float g[4];
#pragma unroll
    for (int r = 0; r < 4; r++) {
      float xt = fminf(acc[0][jn][r], 40.f);
      float A = __expf(2.f * xt);
      float Bs = __expf(-acc[1][jn][r]);
      g[r] = (A - 1.f) * __builtin_amdgcn_rcpf((A + 1.f) * (1.f + Bs));
    }
    unsigned int u0 = cvt_pk_bf16(g[0], g[1]);
    unsigned int u1 = cvt_pk_bf16(g[2], g[3]);
    if (tb + col < 0) { u0 = 0; u1 = 0; }
    *(uint2v*)(gb + col * GSTE + wm * 16 + q * 4) = (uint2v){u0, u1};
  }
}

template<int G0, int GN>
__device__ __forceinline__ void res_upd_grp(
    const unsigned short* __restrict__ frags, const float* __restrict__ b_res,
    unsigned short* __restrict__ xb, const unsigned short* __restrict__ gb,
    int layer, int tb, int colbase, int wm, int lane, int q)
{
  f32x4 acc[2][GN];
#pragma unroll
  for (int i = 0; i < 2; i++) {
    f32x4 bv = *(const f32x4*)(b_res + layer * 128 + (wm + 4 * i) * 16 + q * 4);
#pragma unroll
    for (int jn = 0; jn < GN; jn++) acc[i][jn] = bv;
  }
#pragma unroll
  for (int kc = 0; kc < 2; kc++) {
    short8 a0 = *(const short8*)(frags + FR + (((layer * 8 + wm    ) * 2 + kc) * 64 + lane) * 8);
    short8 a1 = *(const short8*)(frags + FR + (((layer * 8 + wm + 4) * 2 + kc) * 64 + lane) * 8);
#pragma unroll
    for (int jn = 0; jn < GN; jn++) {
      int col = colbase + (G0 + jn) * 16;
      short8 bv = *(const short8*)(gb + col * GSTE + kc * 32 + q * 8);
      acc[0][jn] = MFMA(a0, bv, acc[0][jn]);
      acc[1][jn] = MFMA(a1, bv, acc[1][jn]);
    }
  }
#pragma unroll
  for (int i = 0; i < 2; i++) {
#pragma unroll
    for (int jn = 0; jn < GN; jn++) {
      int col = colbase + (G0 + jn) * 16;
      unsigned short* p = xb + col * XSTE + (wm + 4 * i) * 16 + q * 4;
      uint2v old = *(const uint2v*)p;
      float x0 = __builtin_bit_cast(float, old[0] << 16);
      float x1 = __builtin_bit_cast(float, old[0] & 0xffff0000u);
      float x2 = __builtin_bit_cast(float, old[1] << 16);
      float x3 = __builtin_bit_cast(float, old[1] & 0xffff0000u);
      unsigned int u0 = cvt_pk_bf16(acc[i][jn][0] + x0, acc[i][jn][1] + x1);
      unsigned int u1 = cvt_pk_bf16(acc[i][jn][2] + x2, acc[i][jn][3] + x3);
      if (tb + col < 0) { u0 = 0; u1 = 0; }
      *(uint2v*)p = (uint2v){u0, u1};
    }
  }
}

// ------------------------------- main kernel -------------------------------
extern "C" __global__ void __launch_bounds__(512, 4) wavenet_main(
    const int* __restrict__ tokens,
    const unsigned short* __restrict__ embf,
    const unsigned short* __restrict__ frags,
    const float* __restrict__ bsk,
    const float* __restrict__ b_init,
    const float* __restrict__ b_dil,
    const float* __restrict__ b_res,
    const float* __restrict__ b_out1,
    const float* __restrict__ b_out2,
    float* __restrict__ out)
{
  extern __shared__ char lds[];
  unsigned short* xb = (unsigned short*)(lds + X_OFF);  // [96][136] x (bf16)
  unsigned short* gb = (unsigned short*)(lds + G_OFF);  // [96][72]  g (bf16)
  unsigned short* sb = (unsigned short*)(lds + S_OFF);  // [64][264] s/t1 (overlay)

  const int tid = threadIdx.x;
  const int lane = tid & 63;
  const int w = tid >> 6;        // 0..7
  const int l16 = lane & 15;
  const int q = lane >> 4;
  const int wm = w & 3;          // conv M-group: M-tiles {wm, wm+4} (gate pairing)
  const int wn = w >> 2;         // conv N-group (0..1)
  const int bb = blockIdx.x >> 7;      // 128 chunks per batch
  const int chunk = blockIdx.x & 127;
  const int tb = chunk * TT - HALO;    // abs t of buffer col 0
  const int colbase = wn * 48 + l16;   // ncol(jn) = colbase + jn*16, jn=0..2

  f32x4 sk[2][4];    // persistent skip accumulators (then out1/out2)

  // ---- phase A: init conv (B-frags gathered straight from bf16 emb copy) ----
  phaseA_grp<0, 3>(tokens, embf, frags, b_init, xb, bb, tb, colbase, wm, lane, q);

  // init persistent skip accumulators with combined bias
#pragma unroll
  for (int i = 0; i < 2; i++) {
    f32x4 bv = *(const f32x4*)(bsk + (2 * w + i) * 16 + q * 4);
#pragma unroll
    for (int jt = 0; jt < 4; jt++) sk[i][jt] = bv;
  }
  __syncthreads();

  // ---- 12 layers ----
  for (int layer = 0; layer < 12; layer++) {
    dil_gate_grp<0, 3>(frags, b_dil, xb, gb, layer, tb, colbase, wm, lane, q);
    __syncthreads();
    // skip GEMM into persistent accumulators (central 64 cols only)
#pragma unroll
    for (int kc = 0; kc < 2; kc++) {
      short8 a0 = *(const short8*)(frags + FS + (((layer * 16 + 2 * w    ) * 2 + kc) * 64 + lane) * 8);
      short8 a1 = *(const short8*)(frags + FS + (((layer * 16 + 2 * w + 1) * 2 + kc) * 64 + lane) * 8);
#pragma unroll
      for (int jt = 0; jt < 4; jt++) {
        short8 bv = *(const short8*)(gb + (HALO + jt * 16 + l16) * GSTE + kc * 32 + q * 8);
        sk[0][jt] = MFMA(a0, bv, sk[0][jt]);
        sk[1][jt] = MFMA(a1, bv, sk[1][jt]);
      }
    }
    // res GEMM (all 96 cols) then x += res
    res_upd_grp<0, 3>(frags, b_res, xb, gb, layer, tb, colbase, wm, lane, q);
    __syncthreads();
  }

  // ---- epilogue: s = relu(skip_mean) -> out1 -> relu -> out2 ----
  // sb overlays xb/gb; all xb/gb reads completed before the final layer barrier.
#pragma unroll
  for (int i = 0; i < 2; i++) {
#pragma unroll
    for (int jt = 0; jt < 4; jt++) {
      unsigned int u0 = cvt_pk_bf16(fmaxf(sk[i][jt][0], 0.f), fmaxf(sk[i][jt][1], 0.f));
      unsigned int u1 = cvt_pk_bf16(fmaxf(sk[i][jt][2], 0.f), fmaxf(sk[i][jt][3], 0.f));
      *(uint2v*)(sb + (jt * 16 + l16) * SSTE + (2 * w + i) * 16 + q * 4) = (uint2v){u0, u1};
    }
  }
  __syncthreads();
  // out1
#pragma unroll
  for (int i = 0; i < 2; i++) {
    f32x4 bv = *(const f32x4*)(b_out1 + (2 * w + i) * 16 + q * 4);
#pragma unroll
    for (int jt = 0; jt < 4; jt++) sk[i][jt] = bv;
  }
#pragma unroll
  for (int kc = 0; kc < 8; kc++) {
    short8 a0 = *(const short8*)(frags + FO1 + (((2 * w    ) * 8 + kc) * 64 + lane) * 8);
    short8 a1 = *(const short8*)(frags + FO1 + (((2 * w + 1) * 8 + kc) * 64 + lane) * 8);
#pragma unroll
    for (int jt = 0; jt < 4; jt++) {
      short8 bv = *(const short8*)(sb + (jt * 16 + l16) * SSTE + kc * 32 + q * 8);
      sk[0][jt] = MFMA(a0, bv, sk[0][jt]);
      sk[1][jt] = MFMA(a1, bv, sk[1][jt]);
    }
  }
  unsigned int t1p[2][4][2];
#pragma unroll
  for (int i = 0; i < 2; i++) {
#pragma unroll
    for (int jt = 0; jt < 4; jt++) {
      t1p[i][jt][0] = cvt_pk_bf16(fmaxf(sk[i][jt][0], 0.f), fmaxf(sk[i][jt][1], 0.f));
      t1p[i][jt][1] = cvt_pk_bf16(fmaxf(sk[i][jt][2], 0.f), fmaxf(sk[i][jt][3], 0.f));
    }
  }
  __syncthreads();   // all reads of s done before overwrite
#pragma unroll
  for (int i = 0; i < 2; i++) {
#pragma unroll
    for (int jt = 0; jt < 4; jt++)
      *(uint2v*)(sb + (jt * 16 + l16) * SSTE + (2 * w + i) * 16 + q * 4) =
          (uint2v){t1p[i][jt][0], t1p[i][jt][1]};
  }
  __syncthreads();
  // out2
#pragma unroll
  for (int i = 0; i < 2; i++) {
    f32x4 bv = *(const f32x4*)(b_out2 + (2 * w + i) * 16 + q * 4);
#pragma unroll
    for (int jt = 0; jt < 4; jt++) sk[i][jt] = bv;
  }
#pragma unroll
  for (int kc = 0; kc < 8; kc++) {
    short8 a0 = *(const short8*)(frags + FO2 + (((2 * w    ) * 8 + kc) * 64 + lane) * 8);
    short8 a1 = *(const short8*)(frags + FO2 + (((2 * w + 1) * 8 + kc) * 64 + lane) * 8);
#pragma unroll
    for (int jt = 0; jt < 4; jt++) {
      short8 bv = *(const short8*)(sb + (jt * 16 + l16) * SSTE + kc * 32 + q * 8);
      sk[0][jt] = MFMA(a0, bv, sk[0][jt]);
      sk[1][jt] = MFMA(a1, bv, sk[1][jt]);
    }
  }
  // write out [B, V=256, T] as FLOAT32
  const int t0 = chunk * TT;
#pragma unroll
  for (int i = 0; i < 2; i++) {
#pragma unroll
    for (int jt = 0; jt < 4; jt++) {
#pragma unroll
      for (int r = 0; r < 4; r++) {
        int v = (2 * w + i) * 16 + q * 4 + r;
        int t = t0 + jt * 16 + l16;
        out[((size_t)(bb * 256 + v) << 13) + t] = sk[i][jt][r];
      }
    }
  }
}

// ------------------------------- launcher ----------------------------------
extern "C" void kernel_launch(void* const* d_in, const int* in_sizes, int n_in,
                              void* d_out, int out_size, void* d_ws, size_t ws_size,
                              hipStream_t stream) {
  (void)in_sizes; (void)n_in; (void)out_size; (void)ws_size;
  const int*   tokens = (const int*)d_in[0];
  const float* emb    = (const float*)d_in[1];
  const float* w_init = (const float*)d_in[2];
  const float* b_init = (const float*)d_in[3];
  const float* w_dil  = (const float*)d_in[4];
  const float* b_dil  = (const float*)d_in[5];
  const float* w_res  = (const float*)d_in[6];
  const float* b_res  = (const float*)d_in[7];
  const float* w_skip = (const float*)d_in[8];
  const float* b_skip = (const float*)d_in[9];
  const float* w_out1 = (const float*)d_in[10];
  const float* b_out1 = (const float*)d_in[11];
  const float* w_out2 = (const float*)d_in[12];
  const float* b_out2 = (const float*)d_in[13];

  unsigned short* frags = (unsigned short*)d_ws;
  float* bsk = (float*)((char*)d_ws + BSK_BYTE_OFF);
  unsigned short* embf = (unsigned short*)((char*)d_ws + EMBF_BYTE_OFF);

  prep_kernel<<<dim3(PREP_TOTAL / 256), dim3(256), 0, stream>>>(
      emb, w_init, w_dil, w_skip, w_res, w_out1, w_out2, b_skip,
      frags, bsk, embf);

  // opt-in to >64KB dynamic LDS (no-op/harmless where already allowed)
  (void)hipFuncSetAttribute((const void*)wavenet_main,
                            hipFuncAttributeMaxDynamicSharedMemorySize, LDS_BYTES);

  wavenet_main<<<dim3(2048), dim3(512), LDS_BYTES, stream>>>(
      tokens, embf, frags, bsk, b_init, b_dil, b_res, b_out1, b_out2,
      (float*)d_out);
}